// Round 10
// baseline (78.747 us; speedup 1.0000x reference)
//
#include <hip/hip_runtime.h>
#include <hip/hip_bf16.h>

// EdgeConv: B=8, C=64, N=4096, K=16, O=64
// Key identity: out[n] = relu(F[n] + max_k G[src[n,k]]),
//   F = x@(Wa-Wb)+bias, G = x@Wb   (max commutes with lane-constant add; relu with max)
// k1: dense GEMM -> FG[B*N][128] bf16 (cols 0-63 = F, 64-127 = G)
// k2: per-node wave, half-wave ushort2 gathers (one instr = two full G rows).
//
// Locality model (R6 vs R8/R9 evidence): under round-robin block->XCD dispatch,
// b = bid&7 pins batch b's blocks to XCD b in BOTH kernels -> each XCD's gather
// working set is its own 1 MB FG slice (fits 4 MB L2) -> L2-hit gathers (R6: 6.8us
// replay). Plain mapping spreads 8 MB over every XCD's L2 -> thrash (R8/R9: 24us).
// Writer-side __threadfence() at fg_gemm exit (release) guards cross-L2 visibility;
// NO reader-side fence (R7: per-block acquire-invalidate thrashed L2, 82us).

#define BB 8
#define CC 64
#define NN 4096
#define KK 16
#define OO 64

typedef __bf16 bf16x8 __attribute__((ext_vector_type(8)));
typedef float f32x4 __attribute__((ext_vector_type(4)));

union Frag { int4 i; bf16x8 v; };
union PackA { bf16x8 v; __hip_bfloat16 h[8]; };

// ---------------- k1: FG = [x@(Wa-Wb)+bias | x@Wb] ----------------
// Block: 64 nodes of one batch. M=64, N2=128, K=64. 4 waves, 16 MFMA each.
__global__ __launch_bounds__(256, 3) void fg_gemm(
    const float* __restrict__ x, const float* __restrict__ W,
    const float* __restrict__ bias, __hip_bfloat16* __restrict__ FG) {
    __shared__ float xt[64][65];      // [c][node] f32, +1 pad
    __shared__ int4 wfl[16][64];      // B-frags: [ks*8+ot][lane]

    int t = threadIdx.x, w = t >> 6, l = t & 63;
    int b = blockIdx.x & 7;           // XCD swizzle: batch b -> XCD b (round-robin dispatch)
    int n0 = (blockIdx.x >> 3) << 6;

    // load x tile (float4, coalesced along n)
    const float* xb = x + (size_t)b * CC * NN;
    #pragma unroll
    for (int it = 0; it < 4; ++it) {
        int idx = it * 256 + t;       // 1024 float4 = 64 rows x 16
        int c = idx >> 4, q = idx & 15;
        float4 v = *(const float4*)(xb + (size_t)c * NN + n0 + q * 4);
        xt[c][q * 4 + 0] = v.x; xt[c][q * 4 + 1] = v.y;
        xt[c][q * 4 + 2] = v.z; xt[c][q * 4 + 3] = v.w;
    }
    // build Wcmb B-fragments: Wcmb[k][o2] = (o2<64 ? Wa-Wb : Wb)[k][o2&63]
    {
        __hip_bfloat16* wlu = (__hip_bfloat16*)wfl;
        int o = t & 63, h = t >> 6;
        #pragma unroll
        for (int kk = 0; kk < 16; ++kk) {
            int k = h * 16 + kk;
            float wa = W[k * OO + o];          // coalesced (o consecutive)
            float wb = W[(64 + k) * OO + o];
            int g = (k >> 3) & 3, j = k & 7, ks = k >> 5;
            int lane = (g << 4) | (o & 15);
            int fsA = ks * 8 + (o >> 4);       // o2 = o      (F part)
            int fsB = fsA + 4;                 // o2 = 64 + o (G part)
            wlu[((fsA * 64 + lane) << 3) | j] = __float2bfloat16(wa - wb);
            wlu[((fsB * 64 + lane) << 3) | j] = __float2bfloat16(wb);
        }
    }
    __syncthreads();

    Frag wf[2][8];
    #pragma unroll
    for (int ks = 0; ks < 2; ++ks)
        #pragma unroll
        for (int ot = 0; ot < 8; ++ot)
            wf[ks][ot].i = wfl[ks * 8 + ot][l];

    f32x4 acc[8];
    #pragma unroll
    for (int ot = 0; ot < 8; ++ot) {
        float bv = (ot < 4) ? bias[ot * 16 + (l & 15)] : 0.0f;
        acc[ot] = f32x4{bv, bv, bv, bv};
    }

    int node = (w << 4) + (l & 15);   // A row = lane&15
    #pragma unroll
    for (int ks = 0; ks < 2; ++ks) {
        PackA a;
        #pragma unroll
        for (int j = 0; j < 8; ++j)
            a.h[j] = __float2bfloat16(xt[ks * 32 + ((l >> 4) << 3) + j][node]);
        #pragma unroll
        for (int ot = 0; ot < 8; ++ot)
            acc[ot] = __builtin_amdgcn_mfma_f32_16x16x32_bf16(a.v, wf[ks][ot].v, acc[ot], 0, 0, 0);
    }

    // D: col = lane&15, row = (lane>>4)*4 + r  (m89-verified layout)
    size_t base = ((size_t)b * NN + n0 + (w << 4)) * 128;
    #pragma unroll
    for (int ot = 0; ot < 8; ++ot)
        #pragma unroll
        for (int r = 0; r < 4; ++r) {
            int nd = ((l >> 4) << 2) + r;
            FG[base + (size_t)nd * 128 + ot * 16 + (l & 15)] = __float2bfloat16(acc[ot][r]);
        }
    __threadfence();   // writer-side release only: FG visible at device scope
}

// ---------------- k2: out[b][o][n] = relu(F[n][o] + max_k G[src[n][k]][o]) ----------------
// Half-wave gather: lanes 0-31 = even edges, 32-63 = odd edges; each lane loads
// ushort2 (2 channels). One instr fetches TWO full 128B G rows. Parities combine
// via shfl_xor(32). bf16->f32 is free bit-masking on the packed uint.
__global__ __launch_bounds__(256, 4) void gather_max(
    const int* __restrict__ ei, const unsigned int* __restrict__ FG2,
    float* __restrict__ out) {
    __shared__ float otile[64][33];   // [o][node_local]
    int t = threadIdx.x, w = t >> 6, l = t & 63;
    int b = blockIdx.x & 7;           // XCD swizzle: same batch->XCD pinning as fg_gemm
    int n0 = (blockIdx.x >> 3) << 5;

    const int* srcp = ei + (size_t)b * NN * KK;   // ei[0][b]
    size_t bbase = (size_t)b * NN;
    int nb = n0 + (w << 3);
    int h = l >> 5;                   // edge parity handled by this half-wave
    int cp = l & 31;                  // channel-pair index (channels 2cp, 2cp+1)

    int idxv[8];
    #pragma unroll
    for (int i = 0; i < 8; ++i) idxv[i] = srcp[(nb + i) * KK + (l & 15)];

    unsigned int fv[8];               // F channels (2cp,2cp+1), rows = own nodes
    #pragma unroll
    for (int i = 0; i < 8; ++i) fv[i] = FG2[((bbase + nb + i) << 6) + cp];

    #pragma unroll
    for (int i = 0; i < 8; ++i) {
        unsigned int g[8];
        #pragma unroll
        for (int j = 0; j < 8; ++j) {
            int vk = __shfl(idxv[i], (j << 1) | h);   // edge 2j+h's src node
            g[j] = FG2[(((size_t)bbase + vk) << 6) + 32 + cp];
        }
        float m0 = -3.4e38f, m1 = -3.4e38f;
        #pragma unroll
        for (int j = 0; j < 8; ++j) {
            m0 = fmaxf(m0, __uint_as_float(g[j] << 16));          // low bf16
            m1 = fmaxf(m1, __uint_as_float(g[j] & 0xffff0000u));  // high bf16
        }
        m0 = fmaxf(m0, __shfl_xor(m0, 32));   // combine edge parities
        m1 = fmaxf(m1, __shfl_xor(m1, 32));
        if (!h) {
            int nl = (w << 3) + i;
            otile[2 * cp + 0][nl] = fmaxf(__uint_as_float(fv[i] << 16) + m0, 0.0f);
            otile[2 * cp + 1][nl] = fmaxf(__uint_as_float(fv[i] & 0xffff0000u) + m1, 0.0f);
        }
    }
    __syncthreads();

    float* ob = out + (size_t)b * OO * NN;
    #pragma unroll
    for (int it = 0; it < 8; ++it) {
        int idx = it * 256 + t, o = idx >> 5, nn = idx & 31;
        ob[(size_t)o * NN + n0 + nn] = otile[o][nn];            // coalesced 128B rows
    }
}

extern "C" void kernel_launch(void* const* d_in, const int* in_sizes, int n_in,
                              void* d_out, int out_size, void* d_ws, size_t ws_size,
                              hipStream_t stream) {
    const float* x    = (const float*)d_in[0];   // [B,C,N,1] f32
    const int*   ei   = (const int*)d_in[1];     // [2,B,N,K] i32
    const float* W    = (const float*)d_in[2];   // [128,64] f32
    const float* bias = (const float*)d_in[3];   // [64] f32
    float* out = (float*)d_out;                  // [B,O,N,1] f32

    __hip_bfloat16* FG = (__hip_bfloat16*)d_ws;  // [B*N][128] bf16 = 8 MB

    hipLaunchKernelGGL(fg_gemm, dim3(BB * (NN / 64)), dim3(256), 0, stream,
                       x, W, bias, FG);
    hipLaunchKernelGGL(gather_max, dim3(BB * (NN / 32)), dim3(256), 0, stream,
                       ei, (const unsigned int*)FG, out);
}

// Round 11
// 24.579 us; speedup vs baseline: 3.2038x; 3.2038x over previous
//
#include <hip/hip_runtime.h>
#include <hip/hip_bf16.h>

// EdgeConv: B=8, C=64, N=4096, K=16, O=64
// Key identity: out[n] = relu(F[n] + max_k G[src[n,k]]),
//   F = x@(Wa-Wb)+bias, G = x@Wb   (max commutes with lane-constant add; relu with max)
// k1: dense GEMM -> FG[B*N][128] bf16 (cols 0-63 = F, 64-127 = G)
// k2: per-wave 8 nodes, ALL 32 uint2 gathers issued upfront (max MLP), then reduce.
//
// Hard-won correctness/perf config (R6/R7/R10 evidence):
//  - plain block mapping; NO XCD swizzle (R6: post-timing stale-G divergence; R10:
//    swizzle gives zero gather speedup anyway)
//  - NO __threadfence() anywhere (R7 reader fence: 82us; R10 writer fence: 60us;
//    same-stream dispatch ordering provides the needed release/acquire)

#define BB 8
#define CC 64
#define NN 4096
#define KK 16
#define OO 64

typedef __bf16 bf16x8 __attribute__((ext_vector_type(8)));
typedef float f32x4 __attribute__((ext_vector_type(4)));

union Frag { int4 i; bf16x8 v; };
union PackA { bf16x8 v; __hip_bfloat16 h[8]; };

// ---------------- k1: FG = [x@(Wa-Wb)+bias | x@Wb] ----------------
// Block: 64 nodes of one batch. M=64, N2=128, K=64. 4 waves, 16 MFMA each.
__global__ __launch_bounds__(256, 3) void fg_gemm(
    const float* __restrict__ x, const float* __restrict__ W,
    const float* __restrict__ bias, __hip_bfloat16* __restrict__ FG) {
    __shared__ float xt[64][65];      // [c][node] f32, +1 pad
    __shared__ int4 wfl[16][64];      // B-frags: [ks*8+ot][lane]

    int t = threadIdx.x, w = t >> 6, l = t & 63;
    int b = blockIdx.x >> 6;          // plain mapping
    int n0 = (blockIdx.x & 63) << 6;

    // load x tile (float4, coalesced along n)
    const float* xb = x + (size_t)b * CC * NN;
    #pragma unroll
    for (int it = 0; it < 4; ++it) {
        int idx = it * 256 + t;       // 1024 float4 = 64 rows x 16
        int c = idx >> 4, q = idx & 15;
        float4 v = *(const float4*)(xb + (size_t)c * NN + n0 + q * 4);
        xt[c][q * 4 + 0] = v.x; xt[c][q * 4 + 1] = v.y;
        xt[c][q * 4 + 2] = v.z; xt[c][q * 4 + 3] = v.w;
    }
    // build Wcmb B-fragments: Wcmb[k][o2] = (o2<64 ? Wa-Wb : Wb)[k][o2&63]
    {
        __hip_bfloat16* wlu = (__hip_bfloat16*)wfl;
        int o = t & 63, h = t >> 6;
        #pragma unroll
        for (int kk = 0; kk < 16; ++kk) {
            int k = h * 16 + kk;
            float wa = W[k * OO + o];          // coalesced (o consecutive)
            float wb = W[(64 + k) * OO + o];
            int g = (k >> 3) & 3, j = k & 7, ks = k >> 5;
            int lane = (g << 4) | (o & 15);
            int fsA = ks * 8 + (o >> 4);       // o2 = o      (F part)
            int fsB = fsA + 4;                 // o2 = 64 + o (G part)
            wlu[((fsA * 64 + lane) << 3) | j] = __float2bfloat16(wa - wb);
            wlu[((fsB * 64 + lane) << 3) | j] = __float2bfloat16(wb);
        }
    }
    __syncthreads();

    Frag wf[2][8];
    #pragma unroll
    for (int ks = 0; ks < 2; ++ks)
        #pragma unroll
        for (int ot = 0; ot < 8; ++ot)
            wf[ks][ot].i = wfl[ks * 8 + ot][l];

    f32x4 acc[8];
    #pragma unroll
    for (int ot = 0; ot < 8; ++ot) {
        float bv = (ot < 4) ? bias[ot * 16 + (l & 15)] : 0.0f;
        acc[ot] = f32x4{bv, bv, bv, bv};
    }

    int node = (w << 4) + (l & 15);   // A row = lane&15
    #pragma unroll
    for (int ks = 0; ks < 2; ++ks) {
        PackA a;
        #pragma unroll
        for (int j = 0; j < 8; ++j)
            a.h[j] = __float2bfloat16(xt[ks * 32 + ((l >> 4) << 3) + j][node]);
        #pragma unroll
        for (int ot = 0; ot < 8; ++ot)
            acc[ot] = __builtin_amdgcn_mfma_f32_16x16x32_bf16(a.v, wf[ks][ot].v, acc[ot], 0, 0, 0);
    }

    // D: col = lane&15, row = (lane>>4)*4 + r  (m89-verified layout)
    size_t base = ((size_t)b * NN + n0 + (w << 4)) * 128;
    #pragma unroll
    for (int ot = 0; ot < 8; ++ot)
        #pragma unroll
        for (int r = 0; r < 4; ++r) {
            int nd = ((l >> 4) << 2) + r;
            FG[base + (size_t)nd * 128 + ot * 16 + (l & 15)] = __float2bfloat16(acc[ot][r]);
        }
}

// ---------------- k2: out[b][o][n] = relu(F[n][o] + max_k G[src[n][k]][o]) ----------------
// Wave = 8 nodes. uint2 gathers: instr (i,q) fetches 4 full G-rows (lanes: eg=l>>4
// picks row, c=l&15 picks 4 channels). ALL 32 gathers issued before any reduction
// -> 32 x 512B in flight per wave (4x the compiler's default pipelining).
__global__ __launch_bounds__(256, 4) void gather_max(
    const int* __restrict__ ei, const uint2* __restrict__ FGq,
    float* __restrict__ out) {
    __shared__ float otile[64][33];   // [o][node_local]
    int t = threadIdx.x, w = t >> 6, l = t & 63;
    int b = blockIdx.x >> 7;          // plain mapping
    int n0 = (blockIdx.x & 127) << 5;

    const int* srcp = ei + (size_t)b * NN * KK;   // ei[0][b]
    size_t bbase = (size_t)b * NN;
    int nb = n0 + (w << 3);           // 8 nodes for this wave
    int eg = l >> 4;                  // row subgroup 0..3
    int c  = l & 15;                  // uint2 index within half-row (channels 4c..4c+3)

    int idxv[8];                      // lane c holds src[n][c] (edges 0..15 in lanes 0..15)
    #pragma unroll
    for (int i = 0; i < 8; ++i) idxv[i] = srcp[(nb + i) * KK + c];

    // F rows, lane-parallel: lane covers node nb+p*4+eg, channels 4c..4c+3
    uint2 fv[2];
    #pragma unroll
    for (int p = 0; p < 2; ++p) fv[p] = FGq[(bbase + nb + (p << 2) + eg) * 32 + c];

    // all 32 gathers upfront: g[i][q] = G-row of edge (q*4+eg) of node i, chans 4c..4c+3
    uint2 g[8][4];
    #pragma unroll
    for (int i = 0; i < 8; ++i)
        #pragma unroll
        for (int q = 0; q < 4; ++q) {
            int vk = __shfl(idxv[i], (q << 2) | eg);
            g[i][q] = FGq[((size_t)bbase + vk) * 32 + 16 + c];
        }

    #pragma unroll
    for (int i = 0; i < 8; ++i) {
        float m0 = -3.4e38f, m1 = -3.4e38f, m2 = -3.4e38f, m3 = -3.4e38f;
        #pragma unroll
        for (int q = 0; q < 4; ++q) {
            m0 = fmaxf(m0, __uint_as_float(g[i][q].x << 16));
            m1 = fmaxf(m1, __uint_as_float(g[i][q].x & 0xffff0000u));
            m2 = fmaxf(m2, __uint_as_float(g[i][q].y << 16));
            m3 = fmaxf(m3, __uint_as_float(g[i][q].y & 0xffff0000u));
        }
        // combine the 4 row subgroups (lanes l^16, l^32 hold same channels)
        m0 = fmaxf(m0, __shfl_xor(m0, 16)); m0 = fmaxf(m0, __shfl_xor(m0, 32));
        m1 = fmaxf(m1, __shfl_xor(m1, 16)); m1 = fmaxf(m1, __shfl_xor(m1, 32));
        m2 = fmaxf(m2, __shfl_xor(m2, 16)); m2 = fmaxf(m2, __shfl_xor(m2, 32));
        m3 = fmaxf(m3, __shfl_xor(m3, 16)); m3 = fmaxf(m3, __shfl_xor(m3, 32));
        if (eg == (i & 3)) {          // this lane-group holds node i's F row
            uint2 f = fv[i >> 2];
            int nl = (w << 3) + i;
            otile[4 * c + 0][nl] = fmaxf(__uint_as_float(f.x << 16) + m0, 0.0f);
            otile[4 * c + 1][nl] = fmaxf(__uint_as_float(f.x & 0xffff0000u) + m1, 0.0f);
            otile[4 * c + 2][nl] = fmaxf(__uint_as_float(f.y << 16) + m2, 0.0f);
            otile[4 * c + 3][nl] = fmaxf(__uint_as_float(f.y & 0xffff0000u) + m3, 0.0f);
        }
    }
    __syncthreads();

    float* ob = out + (size_t)b * OO * NN;
    #pragma unroll
    for (int it = 0; it < 8; ++it) {
        int idx = it * 256 + t, o = idx >> 5, nn = idx & 31;
        ob[(size_t)o * NN + n0 + nn] = otile[o][nn];            // coalesced 128B rows
    }
}

extern "C" void kernel_launch(void* const* d_in, const int* in_sizes, int n_in,
                              void* d_out, int out_size, void* d_ws, size_t ws_size,
                              hipStream_t stream) {
    const float* x    = (const float*)d_in[0];   // [B,C,N,1] f32
    const int*   ei   = (const int*)d_in[1];     // [2,B,N,K] i32
    const float* W    = (const float*)d_in[2];   // [128,64] f32
    const float* bias = (const float*)d_in[3];   // [64] f32
    float* out = (float*)d_out;                  // [B,O,N,1] f32

    __hip_bfloat16* FG = (__hip_bfloat16*)d_ws;  // [B*N][128] bf16 = 8 MB

    hipLaunchKernelGGL(fg_gemm, dim3(BB * (NN / 64)), dim3(256), 0, stream,
                       x, W, bias, FG);
    hipLaunchKernelGGL(gather_max, dim3(BB * (NN / 32)), dim3(256), 0, stream,
                       ei, (const uint2*)FG, out);
}